// Round 16
// baseline (316.670 us; speedup 1.0000x reference)
//
#include <hip/hip_runtime.h>

#define DEV static __device__ __forceinline__

constexpr int BATCH = 256;

DEV float leakyf(float x){ return x > 0.f ? x : 0.2f * x; }

typedef _Float16 f16x8 __attribute__((ext_vector_type(8)));
typedef float f32x4 __attribute__((ext_vector_type(4)));

// ------- pack OIHW conv weights into MFMA B-fragment order, single fp16 -----
template<int IC,int OC>
__global__ __launch_bounds__(256) void wpackM_k(const float* __restrict__ w,
    _Float16* __restrict__ wp){
  constexpr int S = IC/32, F = OC/16;
  int i = blockIdx.x*256 + threadIdx.x;
  if (i >= 9*S*F*512) return;
  int j = i & 7, L = (i >> 3) & 63, rest = i >> 9;
  int f = rest % F; int q2 = rest / F; int s = q2 % S; int t = q2 / S;
  int oc = f*16 + (L & 15), ic = s*32 + (L >> 4)*8 + j;
  wp[i] = (_Float16)w[((size_t)oc*IC + ic)*9 + t];
}

// ------- pack strided-conv weights (IC=16), single fp16 ---------------------
template<int OC,int K>
__global__ __launch_bounds__(256) void wpackS_k(const float* __restrict__ w,
    _Float16* __restrict__ wp){
  constexpr int F = OC/16, KWP = (K+1)/2;
  int i = blockIdx.x*256 + threadIdx.x;
  if (i >= K*KWP*F*512) return;
  int j = i & 7, L = (i >> 3) & 63, rest = i >> 9;
  int f = rest % F, s = rest / F;
  int kh = s / KWP, kwp = s % KWP;
  int k = (L >> 4)*8 + j;
  int kw = 2*kwp + (k >> 4), ic = k & 15;
  int oc = f*16 + (L & 15);
  float v = (kw < K) ? w[((size_t)(oc*16 + ic)*K + kh)*K + kw] : 0.f;
  wp[i] = (_Float16)v;
}

// ------- pack scout1(k7) + conv1(k3) weights, space-to-depth, single fp16 ---
__global__ __launch_bounds__(256) void wpackF_k(const float* __restrict__ sw1,
    const float* __restrict__ tw1, _Float16* __restrict__ wp){
  int i = blockIdx.x*256 + threadIdx.x;
  if (i >= 6*2*512) return;
  int j = i & 7, L = (i >> 3) & 63, rest = i >> 9;
  int nf = rest & 1, s = rest >> 1;
  int k = s*32 + (L >> 4)*8 + j;
  int oc = L & 15;
  int t = k / 48, c = k % 48;
  int dr = (t >> 1) - 1, dc = (t & 1) - 1;
  int ic = c >> 4, pr = (c >> 2) & 3, pc = c & 3;
  float v = 0.f;
  if (nf == 0){
    int kh = 4*dr + pr + 3, kw = 4*dc + pc + 3;
    if (kh >= 0 && kh < 7 && kw >= 0 && kw < 7) v = sw1[((oc*3 + ic)*7 + kh)*7 + kw];
  } else {
    int kh = 4*dr + pr + 1, kw = 4*dc + pc + 1;
    if (kh >= 0 && kh < 3 && kw >= 0 && kw < 3) v = tw1[((oc*3 + ic)*3 + kh)*3 + kw];
  }
  wp[i] = (_Float16)v;
}

// ------- pack expert GEMM weights W[e][N][K] into frag order, single fp16 ---
template<int KTOT>
__global__ __launch_bounds__(256) void wpackGh_k(const float* __restrict__ w, int N,
    _Float16* __restrict__ wp){
  const int NF = N >> 4, KT = KTOT >> 5;
  const int total = NF * KT * 512;
  const int e = blockIdx.y;
  w  += (size_t)e * N * KTOT;
  wp += (size_t)e * total;
  int i = blockIdx.x*256 + threadIdx.x;
  if (i >= total) return;
  int j = i & 7, L = (i >> 3) & 63, rest = i >> 9;
  int nf = rest % NF, t = rest / NF;
  int n = nf*16 + (L & 15), k = t*32 + (L >> 4)*8 + j;
  wp[i] = (_Float16)w[(size_t)n*KTOT + k];
}

// ------- convert fp32 array to fp16 ----------------------------------------
__global__ __launch_bounds__(256) void acvt_k(const float* __restrict__ in,
    _Float16* __restrict__ o16, int nelem){
  int i = blockIdx.x*256 + threadIdx.x;
  if (i >= nelem) return;
  o16[i] = (_Float16)in[i];
}

// ---------- fused scout1+conv1, space-to-depth MFMA, LDS-FREE ---------------
// Each A-fragment = two predicated float4 global loads (coalesced across the
// 16 M-lanes). No barriers, no LDS. Block = (n, 2 rows); wave = half-row.
__global__ __launch_bounds__(256) void fusedG_k(
    const float* __restrict__ x,
    const _Float16* __restrict__ W,
    const float* __restrict__ sb, const float* __restrict__ cb_,
    const float* __restrict__ g, const float* __restrict__ bt,
    const float* __restrict__ mn, const float* __restrict__ vr,
    _Float16* __restrict__ s1out, _Float16* __restrict__ c1out){
  const int tid = threadIdx.x;
  const int n = blockIdx.x / 28, oh0 = (blockIdx.x % 28) * 2;
  const int wid = tid >> 6, lane = tid & 63;
  const int rowsel = wid >> 1, half = wid & 1;
  const int row = oh0 + rowsel;
  const int L15 = lane & 15, Lk = lane >> 4;

  const float* xn = x + (size_t)n * 3 * 224 * 224;

  f32x4 acc[2][2];
  #pragma unroll
  for (int mi = 0; mi < 2; ++mi)
    #pragma unroll
    for (int nf = 0; nf < 2; ++nf) acc[mi][nf] = (f32x4){0.f,0.f,0.f,0.f};

  #pragma unroll
  for (int s = 0; s < 6; ++s){
    const int kk = s*32 + Lk*8;
    const int t = kk / 48, c0 = kk - t*48;
    const int ic = c0 >> 4, b = (c0 >> 3) & 1;
    const int ra = t >> 1, ca = t & 1;
    const bool rowOK = (row + ra) >= 1;
    int rx = 4*(row + ra - 1) + 2*b;
    if (rx < 0) rx = 0;
    const float* xr0 = xn + ((size_t)ic*224 + rx)*224;

    f16x8 ah[2];
    #pragma unroll
    for (int mi = 0; mi < 2; ++mi){
      const int ow = half*32 + mi*16 + L15;
      const int owc = ow > 55 ? 55 : ow;
      const int colf = owc + ca - 1;
      float4 lo = {0.f,0.f,0.f,0.f}, hi = {0.f,0.f,0.f,0.f};
      if (rowOK && colf >= 0){
        lo = *(const float4*)(xr0 + 4*colf);
        hi = *(const float4*)(xr0 + 224 + 4*colf);
      }
      f16x8 a;
      a[0]=(_Float16)lo.x; a[1]=(_Float16)lo.y; a[2]=(_Float16)lo.z; a[3]=(_Float16)lo.w;
      a[4]=(_Float16)hi.x; a[5]=(_Float16)hi.y; a[6]=(_Float16)hi.z; a[7]=(_Float16)hi.w;
      ah[mi] = a;
    }
    #pragma unroll
    for (int nf = 0; nf < 2; ++nf){
      const f16x8 bw = *(const f16x8*)(W + (s*2 + nf)*512 + lane*8);
      #pragma unroll
      for (int mi = 0; mi < 2; ++mi)
        acc[mi][nf] = __builtin_amdgcn_mfma_f32_16x16x32_f16(ah[mi], bw, acc[mi][nf], 0,0,0);
    }
  }

  const int oc = L15;
  const float sbv = sb[oc];
  const float scv = g[oc] * __frsqrt_rn(vr[oc] + 1e-5f);
  const float mnv = mn[oc], btv = bt[oc], cbv = cb_[oc];
  #pragma unroll
  for (int mi = 0; mi < 2; ++mi){
    const int owb = half*32 + mi*16 + Lk*4;
    #pragma unroll
    for (int r = 0; r < 4; ++r){
      const int ow = owb + r;
      if (ow >= 56) continue;
      float vs = acc[mi][0][r] + sbv;
      vs = fmaxf((vs - mnv)*scv + btv, 0.f);
      const size_t o = (((size_t)n*56 + row)*56 + ow)*16 + oc;
      s1out[o] = (_Float16)vs;
      c1out[o] = (_Float16)leakyf(acc[mi][1][r] + cbv);
    }
  }
}

// ---------------- strided (S=2) MFMA conv, fp16 NHWC input [B,IH,IW,16] -----
template<int OC,int K,int P,int IH,int IW,int ACT,bool OUT16>
__global__ __launch_bounds__(256) void convS_k(
    const _Float16* __restrict__ in,
    const _Float16* __restrict__ W,
    const float* __restrict__ bias,
    const float* __restrict__ bng, const float* __restrict__ bnb,
    const float* __restrict__ bnm, const float* __restrict__ bnv,
    float* __restrict__ outF, _Float16* __restrict__ outH){
  constexpr int F = OC/16, KWP = (K+1)/2;
  __shared__ __align__(16) _Float16 A[K*60*16];

  const int tid = threadIdx.x;
  const int n = blockIdx.x / 28, oh = blockIdx.x % 28;

  for (int i = tid; i < K*60*2; i += 256){
    int half = i & 1; int p = i >> 1;
    int c = p % 60; int r = p / 60;
    int ih = 2*oh - P + r, iw = c - P;
    int4 v = {0,0,0,0};
    if (ih >= 0 && ih < IH && iw >= 0 && iw < IW)
      v = *(const int4*)(in + (((size_t)n*IH + ih)*IW + iw)*16 + half*8);
    int byte = ((r*60 + c)*32 + half*16) ^ (((c>>1)&7) << 4);
    *(int4*)((char*)A + byte) = v;
  }
  __syncthreads();

  const int wid = tid >> 6, lane = tid & 63;
  const int fsel = wid & 1, mb = wid >> 1;
  const int ow_l = min(mb*16 + (lane & 15), 27);
  const int ic0b = ((lane >> 4) & 1) * 16;
  const int kwo  = (lane >> 4) >> 1;

  f32x4 acc = {0.f,0.f,0.f,0.f};
  #pragma unroll
  for (int kh = 0; kh < K; ++kh){
    #pragma unroll
    for (int kwp = 0; kwp < KWP; ++kwp){
      const int kw = 2*kwp + kwo;
      const int c = 2*ow_l + kw;
      int byte = ((kh*60 + c)*32 + ic0b) ^ (((c>>1)&7) << 4);
      f16x8 a = *(const f16x8*)((const char*)A + byte);
      const int s = kh*KWP + kwp;
      const f16x8 b = *(const f16x8*)(W + (s*F + fsel)*512 + lane*8);
      acc = __builtin_amdgcn_mfma_f32_16x16x32_f16(a, b, acc, 0,0,0);
    }
  }

  const int oc = fsel*16 + (lane & 15);
  float bv = bias[oc], sc = 1.f, mm = 0.f, bb = 0.f;
  if (ACT == 1){
    sc = bng[oc] * __frsqrt_rn(bnv[oc] + 1e-5f);
    mm = bnm[oc]; bb = bnb[oc];
  }
  #pragma unroll
  for (int r = 0; r < 4; ++r){
    const int ow = mb*16 + (lane >> 4)*4 + r;
    if (ow >= 28) continue;
    float v = acc[r] + bv;
    if (ACT == 1) v = fmaxf((v - mm)*sc + bb, 0.f);
    else          v = leakyf(v);
    const size_t o = (((size_t)n*28 + oh)*28 + ow)*OC + oc;
    if (OUT16) outH[o] = (_Float16)v;
    else       outF[o] = v;
  }
}

// ---------------- MFMA single-fp16 3x3 s1 p1 conv on 27x27, padded NHWC -----
template<int IC,int OC,int OUTM>
__global__ __launch_bounds__(256) void convM_k(
    const _Float16* __restrict__ Ag,
    const _Float16* __restrict__ W,
    const float* __restrict__ bias,
    _Float16* __restrict__ OutPad, _Float16* __restrict__ OutNP)
{
  constexpr int S = IC/32, FTOT = OC/16, FW = FTOT/2;
  constexpr int ICB = IC*2, ICG = ICB/16;
  __shared__ __align__(16) char A[4*34*ICB];

  const int tid = threadIdx.x;
  const int bx = blockIdx.x;
  const int n = bx / 14, pr = bx % 14;
  const int oh0 = pr * 2;

  const size_t gbase = ((size_t)n*29) * 29 * IC;
  for (int g = tid; g < 4*34*ICG; g += 256){
    int r = g / (34*ICG);
    int rem = g - r*(34*ICG);
    int c = rem / ICG, q = rem - c*ICG;
    int rp = oh0 + r;
    int4 v = {0,0,0,0};
    if (rp <= 28 && c < 29){
      size_t e = gbase + ((size_t)rp*29 + c)*IC + q*8;
      v = *(const int4*)(Ag + e);
    }
    int off = (r*34 + c)*ICB + q*16;
    int swz = off ^ ((c & 7) << 4);
    *(int4*)(A + swz) = v;
  }
  __syncthreads();

  const int wid = tid >> 6, lane = tid & 63;
  const int rsel = wid & 1, ocq = wid >> 1;
  const int c0 = lane & 15, kg = (lane >> 4) * 16;
  const int colb0 = c0*ICB + kg, colb1 = (16 + c0)*ICB + kg;
  int msk[3];
  #pragma unroll
  for (int kw = 0; kw < 3; ++kw) msk[kw] = ((c0 + kw) & 7) << 4;

  f32x4 acc[2][FW];
  #pragma unroll
  for (int m = 0; m < 2; ++m)
    #pragma unroll
    for (int f = 0; f < FW; ++f) acc[m][f] = (f32x4){0.f,0.f,0.f,0.f};

  #pragma unroll
  for (int kh = 0; kh < 3; ++kh){
    #pragma unroll
    for (int kw = 0; kw < 3; ++kw){
      #pragma unroll
      for (int s = 0; s < S; ++s){
        const int fr0 = (((kh*3 + kw)*S + s)*FTOT + ocq*FW) * 512 + lane*8;
        f16x8 b[FW];
        #pragma unroll
        for (int f = 0; f < FW; ++f)
          b[f] = *(const f16x8*)(W + fr0 + f*512);
        const int base = ((rsel + kh)*34 + kw)*ICB + s*64;
        const int o0 = (base + colb0) ^ msk[kw];
        const int o1 = (base + colb1) ^ msk[kw];
        f16x8 a0 = *(const f16x8*)(A + o0);
        f16x8 a1 = *(const f16x8*)(A + o1);
        #pragma unroll
        for (int f = 0; f < FW; ++f){
          acc[0][f] = __builtin_amdgcn_mfma_f32_16x16x32_f16(a0, b[f], acc[0][f], 0,0,0);
          acc[1][f] = __builtin_amdgcn_mfma_f32_16x16x32_f16(a1, b[f], acc[1][f], 0,0,0);
        }
      }
    }
  }

  const int orow = oh0 + rsel;
  if (orow >= 27) return;
  #pragma unroll
  for (int f = 0; f < FW; ++f){
    const int oc = (ocq*FW + f)*16 + c0;
    const float bv = bias[oc];
    #pragma unroll
    for (int m = 0; m < 2; ++m){
      #pragma unroll
      for (int r = 0; r < 4; ++r){
        const int ow = m*16 + (lane >> 4)*4 + r;
        if (ow >= 27) continue;
        float v = leakyf(acc[m][f][r] + bv);
        if (OUTM == 0){
          OutPad[(((size_t)n*29 + orow+1)*29 + ow+1)*OC + oc] = (_Float16)v;
        } else {
          OutNP[(((size_t)n*27 + orow)*27 + ow)*OC + oc] = (_Float16)v;
        }
      }
    }
  }
}

// ---------------- single-fp16 MFMA GEMM for MoE head ------------------------
template<int KTOT,int ACT,int OUTM>
__global__ __launch_bounds__(256) void gemmH_k(
    const _Float16* __restrict__ A, long strideA,
    const _Float16* __restrict__ W,
    const float* __restrict__ bias, int N,
    _Float16* __restrict__ OutH, float* __restrict__ OutF){
  const int e = blockIdx.z;
  A += (size_t)e * strideA;
  const int NF = N >> 4, KT = KTOT >> 5;
  W += (size_t)e * NF * KT * 512;
  const float* bs = bias + (size_t)e * N;
  const size_t ob = (size_t)e * 256 * N;

  const int tid = threadIdx.x, wid = tid >> 6, lane = tid & 63;
  const int mblk = blockIdx.x * 32;
  const int nf = blockIdx.y * 4 + wid;
  const int r0 = mblk + (lane & 15);
  const int kof = (lane >> 4) * 8;

  f32x4 acc0 = {0,0,0,0}, acc1 = {0,0,0,0};
  for (int t = 0; t < KT; ++t){
    const int k = t*32 + kof;
    f16x8 a0 = *(const f16x8*)(A + (size_t)r0*KTOT + k);
    f16x8 a1 = *(const f16x8*)(A + (size_t)(r0+16)*KTOT + k);
    const f16x8 b = *(const f16x8*)(W + ((size_t)t*NF + nf)*512 + lane*8);
    acc0 = __builtin_amdgcn_mfma_f32_16x16x32_f16(a0, b, acc0, 0,0,0);
    acc1 = __builtin_amdgcn_mfma_f32_16x16x32_f16(a1, b, acc1, 0,0,0);
  }
  const int n = nf*16 + (lane & 15);
  const float bv = bs[n];
  #pragma unroll
  for (int mi = 0; mi < 2; ++mi){
    f32x4 a = mi ? acc1 : acc0;
    #pragma unroll
    for (int r = 0; r < 4; ++r){
      const int m = mblk + mi*16 + (lane >> 4)*4 + r;
      float v = a[r] + bv;
      if (ACT == 1) v = leakyf(v);
      const size_t o = ob + (size_t)m*N + n;
      if (OUTM == 0) OutH[o] = (_Float16)v;
      else           OutF[o] = v;
    }
  }
}

// ------ fp16 NHWC 2x2 s1 maxpool: [B,56,56,16] -> [B,55,55,16] --------------
__global__ __launch_bounds__(256) void poolh_k(const _Float16* __restrict__ in,
                                               _Float16* __restrict__ out){
  int idx = blockIdx.x * 256 + threadIdx.x;
  if (idx >= BATCH * 55 * 55 * 2) return;
  int half = idx & 1; int p = idx >> 1;
  int ow = p % 55; int t = p / 55; int oh = t % 55; int n = t / 55;
  const _Float16* q = in + (((size_t)n*56 + oh)*56 + ow)*16 + half*8;
  f16x8 a = *(const f16x8*)q;
  f16x8 b = *(const f16x8*)(q + 16);
  f16x8 c = *(const f16x8*)(q + 56*16);
  f16x8 d = *(const f16x8*)(q + 57*16);
  f16x8 r;
  #pragma unroll
  for (int j = 0; j < 8; ++j){
    float m = fmaxf(fmaxf((float)a[j], (float)b[j]), fmaxf((float)c[j], (float)d[j]));
    r[j] = (_Float16)m;
  }
  *(f16x8*)(out + (size_t)p*16 + half*8) = r;
}

// ------- pool2: fp16 NHWC [B,28,28,32] -> padded NHWC fp16 [B,29,29,32] -----
__global__ __launch_bounds__(256) void pool2n_k(const _Float16* __restrict__ in,
    _Float16* __restrict__ o16){
  int idx = blockIdx.x*256 + threadIdx.x;
  if (idx >= BATCH*27*27*32) return;
  int ic = idx & 31; int p = idx >> 5;
  int ow = p % 27; int t = p / 27; int oh = t % 27; int n = t / 27;
  const _Float16* b = in + (((size_t)n*28 + oh)*28 + ow)*32 + ic;
  float v = fmaxf(fmaxf((float)b[0], (float)b[32]),
                  fmaxf((float)b[28*32], (float)b[29*32]));
  o16[(((size_t)n*29 + oh+1)*29 + ow+1)*32 + ic] = (_Float16)v;
}

// ---------------- scout gate (fp32 NHWC input [B,28,28,32]) ----------------
__global__ __launch_bounds__(256) void gate_k(const float* __restrict__ s2,
                                              const float* __restrict__ cw,
                                              const float* __restrict__ cb,
                                              float* __restrict__ comb){
  int n = blockIdx.x;
  int tid = threadIdx.x;
  int c = tid & 31;
  int sub = tid >> 5;
  const float* p = s2 + (size_t)n * 784 * 32 + c;
  float s = 0.f;
  for (int i = sub * 98; i < sub * 98 + 98; ++i) s += p[(size_t)i * 32];
  __shared__ float red[32][8];
  red[c][sub] = s;
  __syncthreads();
  if (tid < 32){
    float tot = 0.f;
    #pragma unroll
    for (int k = 0; k < 8; ++k) tot += red[tid][k];
    red[tid][0] = tot / 784.f;
  }
  __syncthreads();
  if (tid == 0){
    float lg[3];
    for (int e = 0; e < 3; ++e){
      float a = cb[e];
      for (int c2 = 0; c2 < 32; ++c2) a += red[c2][0] * cw[e * 32 + c2];
      lg[e] = a;
    }
    float m = fmaxf(lg[0], fmaxf(lg[1], lg[2]));
    float ex[3], sum = 0.f;
    for (int e = 0; e < 3; ++e){ ex[e] = expf(lg[e] - m); sum += ex[e]; }
    float pr[3];
    for (int e = 0; e < 3; ++e) pr[e] = ex[e] / sum;
    int i1 = 0;
    if (pr[1] > pr[0]) i1 = 1;
    if (pr[2] > pr[i1]) i1 = 2;
    int i2 = -1;
    for (int e = 0; e < 3; ++e){
      if (e == i1) continue;
      if (i2 < 0 || pr[e] > pr[i2]) i2 = e;
    }
    float s12 = pr[i1] + pr[i2] + 1e-6f;
    float cmb[3] = {0.f, 0.f, 0.f};
    cmb[i1] = pr[i1] / s12;
    cmb[i2] = pr[i2] / s12;
    comb[n * 3 + 0] = cmb[0];
    comb[n * 3 + 1] = cmb[1];
    comb[n * 3 + 2] = cmb[2];
  }
}

// ------ channel-parallel fused maxpool2s1(27->26) + adaptive avg(26->3) -----
__global__ __launch_bounds__(256) void papool2_k(const _Float16* __restrict__ in,
                                                 float* __restrict__ flat){
  __shared__ float red[2][128][9];
  const int n = blockIdx.x;
  const int tid = threadIdx.x;
  const int h = tid >> 7, c = tid & 127;
  const _Float16* p = in + (size_t)n * 729 * 128 + c;

  float sum[9];
  #pragma unroll
  for (int j = 0; j < 9; ++j) sum[j] = 0.f;

  float prev[27], cur[27];
  const int r0 = h * 13;
  #pragma unroll
  for (int rr = 0; rr < 14; ++rr){
    const int r = r0 + rr;
    #pragma unroll
    for (int cc = 0; cc < 27; ++cc)
      cur[cc] = (float)p[(size_t)(r*27 + cc) * 128];
    if (rr > 0){
      const int pr = r - 1;
      const bool b0 = (pr < 9), b1 = (pr >= 8) && (pr < 18), b2 = (pr >= 17);
      #pragma unroll
      for (int cc = 0; cc < 26; ++cc){
        float v = fmaxf(fmaxf(prev[cc], prev[cc+1]), fmaxf(cur[cc], cur[cc+1]));
        if (b0){
          if (cc < 9)             sum[0] += v;
          if (cc >= 8 && cc < 18) sum[1] += v;
          if (cc >= 17)           sum[2] += v;
        }
        if (b1){
          if (cc < 9)             sum[3] += v;
          if (cc >= 8 && cc < 18) sum[4] += v;
          if (cc >= 17)           sum[5] += v;
        }
        if (b2){
          if (cc < 9)             sum[6] += v;
          if (cc >= 8 && cc < 18) sum[7] += v;
          if (cc >= 17)           sum[8] += v;
        }
      }
    }
    #pragma unroll
    for (int cc = 0; cc < 27; ++cc) prev[cc] = cur[cc];
  }

  #pragma unroll
  for (int j = 0; j < 9; ++j) red[h][c][j] = sum[j];
  __syncthreads();

  if (tid < 128){
    const float rcp[9] = {1.f/81, 1.f/90, 1.f/81, 1.f/90, 1.f/100, 1.f/90,
                          1.f/81, 1.f/90, 1.f/81};
    float* o = flat + (size_t)n * 1152 + tid * 9;
    #pragma unroll
    for (int j = 0; j < 9; ++j)
      o[j] = (red[0][tid][j] + red[1][tid][j]) * rcp[j];
  }
}

// ---------------- final gated combine ----------------
__global__ __launch_bounds__(256) void comb_k(const float* __restrict__ h3,
                                              const float* __restrict__ comb,
                                              float* __restrict__ out){
  int idx = blockIdx.x * 256 + threadIdx.x;
  if (idx >= BATCH * 512) return;
  int o = idx % 512, b = idx / 512;
  float s = 0.f;
  #pragma unroll
  for (int e = 0; e < 3; ++e)
    s += comb[b * 3 + e] * h3[((size_t)e * BATCH + b) * 512 + o];
  out[idx] = s;
}

// ============================================================================
extern "C" void kernel_launch(void* const* d_in, const int* in_sizes, int n_in,
                              void* d_out, int out_size, void* d_ws, size_t ws_size,
                              hipStream_t stream){
  const float* x    = (const float*)d_in[0];
  const float* tw1  = (const float*)d_in[1];  const float* tb1 = (const float*)d_in[2];
  const float* tw2  = (const float*)d_in[3];  const float* tb2 = (const float*)d_in[4];
  const float* tw3  = (const float*)d_in[5];  const float* tb3 = (const float*)d_in[6];
  const float* tw4  = (const float*)d_in[7];  const float* tb4 = (const float*)d_in[8];
  const float* sw1  = (const float*)d_in[9];  const float* sb1 = (const float*)d_in[10];
  const float* bn1g = (const float*)d_in[11]; const float* bn1b = (const float*)d_in[12];
  const float* bn1m = (const float*)d_in[13]; const float* bn1v = (const float*)d_in[14];
  const float* sw2  = (const float*)d_in[15]; const float* sb2 = (const float*)d_in[16];
  const float* bn2g = (const float*)d_in[17]; const float* bn2b = (const float*)d_in[18];
  const float* bn2m = (const float*)d_in[19]; const float* bn2v = (const float*)d_in[20];
  const float* cw   = (const float*)d_in[21]; const float* cb  = (const float*)d_in[22];
  const float* ew1  = (const float*)d_in[23]; const float* eb1 = (const float*)d_in[24];
  const float* ew2  = (const float*)d_in[25]; const float* eb2 = (const float*)d_in[26];
  const float* ew3  = (const float*)d_in[27]; const float* eb3 = (const float*)d_in[28];
  float* out = (float*)d_out;

  // ---- workspace layout (floats), ~157 MB ----
  float* ws = (float*)d_ws;
  size_t off = 0;
  float* comb   = ws + off; off += 768;
  float* flat   = ws + off; off += (size_t)BATCH * 1152;
  float* h3     = ws + off; off += (size_t)BATCH * 3 * 512;
  _Float16* wpk3 = (_Float16*)(ws + off); off += 9216;
  _Float16* wpk4 = (_Float16*)(ws + off); off += 36864;
  _Float16* wp2  = (_Float16*)(ws + off); off += 7680;
  _Float16* wps2 = (_Float16*)(ws + off); off += 3072;
  _Float16* wpf  = (_Float16*)(ws + off); off += 3072;
  off += 16;                                                      // guard pad
  float* bufA   = ws + off; off += 13778944;
  off += 16;                                                      // guard pad
  float* bufB   = ws + off; off += 23887872;
  off += 16;
  (void)ws_size; (void)in_sizes; (void)n_in; (void)out_size;

  // phase aliases (lifetimes disjoint, single-stream ordered)
  _Float16* s1h = (_Float16*)bufA;           // [B,56,56,16] fp16 NHWC
  _Float16* c1h = (_Float16*)bufB;           // [B,56,56,16] fp16 NHWC
  float* s2out  = bufB + 16000000;           // [B,28,28,32] fp32 NHWC (gate path)
  _Float16* p1h = (_Float16*)bufA;           // [B,55,55,16] fp16 NHWC
  _Float16* c2h = (_Float16*)bufB;           // [B,28,28,32] fp16 NHWC
  _Float16* P2 = (_Float16*)(bufB + 8000000);
  _Float16* C3 = (_Float16*)bufA;
  _Float16* c4h = (_Float16*)bufB;           // [B,27,27,128] fp16 NHWC

  // head-phase aliases in bufB (valid after papool2_k) — all fp16
  _Float16* hb = (_Float16*)bufB;
  size_t uo = 0;
  _Float16* ewp1 = hb + uo; uo += 3538944;
  _Float16* ewp2 = hb + uo; uo += 1572864;
  _Float16* ewp3 = hb + uo; uo += 786432;
  _Float16* f16a = hb + uo; uo += 294912;
  _Float16* h1   = hb + uo; uo += 786432;
  _Float16* h2   = hb + uo; uo += 393216;

  dim3 blk(256);

  // ---- weight prep ----
  wpackM_k<32,64>  <<<dim3(72),  blk, 0, stream>>>(tw3, wpk3);
  wpackM_k<64,128> <<<dim3(288), blk, 0, stream>>>(tw4, wpk4);
  wpackS_k<32,5><<<dim3(60), blk, 0, stream>>>(tw2, wp2);
  wpackS_k<32,3><<<dim3(24), blk, 0, stream>>>(sw2, wps2);
  wpackF_k<<<dim3(24), blk, 0, stream>>>(sw1, tw1, wpf);

  // ---- fused scout1 + conv1 -> fp16 NHWC (LDS-free direct-global) ----
  fusedG_k<<<dim3(BATCH*28), blk, 0, stream>>>(
      x, wpf, sb1, tb1, bn1g, bn1b, bn1m, bn1v, s1h, c1h);

  // ---- scout2 (fp32 out for gate) + gate ----
  convS_k<32,3,1,56,56,1,false><<<dim3(BATCH*28), blk, 0, stream>>>(
      s1h, wps2, sb2, bn2g, bn2b, bn2m, bn2v, s2out, nullptr);
  gate_k<<<dim3(256), blk, 0, stream>>>(s2out, cw, cb, comb);

  // ---- pool1 (fp16 NHWC) -> conv2 (fp16 out) ----
  poolh_k<<<dim3((BATCH*55*55*2 + 255)/256), blk, 0, stream>>>(c1h, p1h);
  convS_k<32,5,2,55,55,0,true><<<dim3(BATCH*28), blk, 0, stream>>>(
      p1h, wp2, tb2, nullptr, nullptr, nullptr, nullptr, nullptr, c2h);

  // ---- pool2 (fp16 in) -> padded NHWC fp16 ----
  hipMemsetAsync(P2, 0, (size_t)6889472 * 2, stream);
  pool2n_k<<<dim3((BATCH*27*27*32 + 255)/256), blk, 0, stream>>>(c2h, P2);

  // ---- conv3 (MFMA fp16) -> padded NHWC fp16 ----
  hipMemsetAsync(C3, 0, (size_t)13778944 * 2, stream);
  convM_k<32,64,0><<<dim3(BATCH*14), blk, 0, stream>>>(
      P2, wpk3, tb3, C3, nullptr);

  // ---- conv4 (MFMA fp16) -> fp16 NHWC [B,27,27,128] ----
  convM_k<64,128,1><<<dim3(BATCH*14), blk, 0, stream>>>(
      C3, wpk4, tb4, nullptr, c4h);

  papool2_k<<<dim3(BATCH), blk, 0, stream>>>(c4h, flat);

  // ---- MoE head: pack weights fp16 + convert A, then 3 fp16 MFMA GEMMs ----
  wpackGh_k<1152><<<dim3(4608,3), blk, 0, stream>>>(ew1, 1024, ewp1);
  wpackGh_k<1024><<<dim3(2048,3), blk, 0, stream>>>(ew2,  512, ewp2);
  wpackGh_k< 512><<<dim3(1024,3), blk, 0, stream>>>(ew3,  512, ewp3);
  acvt_k<<<dim3(1152), blk, 0, stream>>>(flat, f16a, BATCH*1152);

  gemmH_k<1152,1,0><<<dim3(8,16,3), blk, 0, stream>>>(
      f16a, 0L, ewp1, eb1, 1024, h1, nullptr);
  gemmH_k<1024,1,0><<<dim3(8,8,3), blk, 0, stream>>>(
      h1, 256L*1024, ewp2, eb2, 512, h2, nullptr);
  gemmH_k< 512,0,1><<<dim3(8,8,3), blk, 0, stream>>>(
      h2, 256L*512, ewp3, eb3, 512, nullptr, h3);

  comb_k<<<dim3(512), blk, 0, stream>>>(h3, comb, out);
}

// Round 17
// 307.063 us; speedup vs baseline: 1.0313x; 1.0313x over previous
//
#include <hip/hip_runtime.h>

#define DEV static __device__ __forceinline__

constexpr int BATCH = 256;

DEV float leakyf(float x){ return x > 0.f ? x : 0.2f * x; }

typedef _Float16 f16x8 __attribute__((ext_vector_type(8)));
typedef float f32x4 __attribute__((ext_vector_type(4)));

// ------- pack OIHW conv weights into MFMA B-fragment order, single fp16 -----
template<int IC,int OC>
__global__ __launch_bounds__(256) void wpackM_k(const float* __restrict__ w,
    _Float16* __restrict__ wp){
  constexpr int S = IC/32, F = OC/16;
  int i = blockIdx.x*256 + threadIdx.x;
  if (i >= 9*S*F*512) return;
  int j = i & 7, L = (i >> 3) & 63, rest = i >> 9;
  int f = rest % F; int q2 = rest / F; int s = q2 % S; int t = q2 / S;
  int oc = f*16 + (L & 15), ic = s*32 + (L >> 4)*8 + j;
  wp[i] = (_Float16)w[((size_t)oc*IC + ic)*9 + t];
}

// ------- pack strided-conv weights (IC=16), single fp16 ---------------------
template<int OC,int K>
__global__ __launch_bounds__(256) void wpackS_k(const float* __restrict__ w,
    _Float16* __restrict__ wp){
  constexpr int F = OC/16, KWP = (K+1)/2;
  int i = blockIdx.x*256 + threadIdx.x;
  if (i >= K*KWP*F*512) return;
  int j = i & 7, L = (i >> 3) & 63, rest = i >> 9;
  int f = rest % F, s = rest / F;
  int kh = s / KWP, kwp = s % KWP;
  int k = (L >> 4)*8 + j;
  int kw = 2*kwp + (k >> 4), ic = k & 15;
  int oc = f*16 + (L & 15);
  float v = (kw < K) ? w[((size_t)(oc*16 + ic)*K + kh)*K + kw] : 0.f;
  wp[i] = (_Float16)v;
}

// ------- pack scout1(k7) + conv1(k3) weights, space-to-depth, single fp16 ---
__global__ __launch_bounds__(256) void wpackF_k(const float* __restrict__ sw1,
    const float* __restrict__ tw1, _Float16* __restrict__ wp){
  int i = blockIdx.x*256 + threadIdx.x;
  if (i >= 6*2*512) return;
  int j = i & 7, L = (i >> 3) & 63, rest = i >> 9;
  int nf = rest & 1, s = rest >> 1;
  int k = s*32 + (L >> 4)*8 + j;
  int oc = L & 15;
  int t = k / 48, c = k % 48;
  int dr = (t >> 1) - 1, dc = (t & 1) - 1;
  int ic = c >> 4, pr = (c >> 2) & 3, pc = c & 3;
  float v = 0.f;
  if (nf == 0){
    int kh = 4*dr + pr + 3, kw = 4*dc + pc + 3;
    if (kh >= 0 && kh < 7 && kw >= 0 && kw < 7) v = sw1[((oc*3 + ic)*7 + kh)*7 + kw];
  } else {
    int kh = 4*dr + pr + 1, kw = 4*dc + pc + 1;
    if (kh >= 0 && kh < 3 && kw >= 0 && kw < 3) v = tw1[((oc*3 + ic)*3 + kh)*3 + kw];
  }
  wp[i] = (_Float16)v;
}

// ------- pack expert GEMM weights W[e][N][K] into frag order, single fp16 ---
template<int KTOT>
__global__ __launch_bounds__(256) void wpackGh_k(const float* __restrict__ w, int N,
    _Float16* __restrict__ wp){
  const int NF = N >> 4, KT = KTOT >> 5;
  const int total = NF * KT * 512;
  const int e = blockIdx.y;
  w  += (size_t)e * N * KTOT;
  wp += (size_t)e * total;
  int i = blockIdx.x*256 + threadIdx.x;
  if (i >= total) return;
  int j = i & 7, L = (i >> 3) & 63, rest = i >> 9;
  int nf = rest % NF, t = rest / NF;
  int n = nf*16 + (L & 15), k = t*32 + (L >> 4)*8 + j;
  wp[i] = (_Float16)w[(size_t)n*KTOT + k];
}

// ------- convert fp32 array to fp16 ----------------------------------------
__global__ __launch_bounds__(256) void acvt_k(const float* __restrict__ in,
    _Float16* __restrict__ o16, int nelem){
  int i = blockIdx.x*256 + threadIdx.x;
  if (i >= nelem) return;
  o16[i] = (_Float16)in[i];
}

// ---------- fused scout1+conv1, space-to-depth MFMA fp16 (2 rows/block) -----
// (round-15 proven version: 22.5 KB LDS, 67% occupancy, ~88.5 us)
__global__ __launch_bounds__(256) void fusedM_k(
    const float* __restrict__ x,
    const _Float16* __restrict__ W,
    const float* __restrict__ sb, const float* __restrict__ cb_,
    const float* __restrict__ g, const float* __restrict__ bt,
    const float* __restrict__ mn, const float* __restrict__ vr,
    _Float16* __restrict__ s1out, _Float16* __restrict__ c1out){
  __shared__ __align__(16) _Float16 Ah[3*58*64];
  const int tid = threadIdx.x;
  const int n = blockIdx.x / 28, oh0 = (blockIdx.x % 28) * 2;

  { // zero LDS tile
    int4* a = (int4*)Ah;
    for (int i = tid; i < 1392; i += 256) a[i] = (int4){0,0,0,0};
  }
  __syncthreads();

  for (int i = tid; i < 2016; i += 256){
    int m = i % 56; int rc = i / 56;
    int ic = rc % 3, ridx = rc / 3;
    int ih = 4*oh0 - 4 + ridx;
    if (ih < 0 || ih >= 224) continue;
    float4 v = *(const float4*)(x + ((size_t)(n*3 + ic)*224 + ih)*224 + 4*m);
    int rr = ridx >> 2, pr = ridx & 3, cc = m + 1;
    int boff = (((rr*58 + cc) << 7) + ic*32 + pr*8) ^ ((cc & 7) << 4);
    _Float16 h4[4] = {(_Float16)v.x, (_Float16)v.y, (_Float16)v.z, (_Float16)v.w};
    *(unsigned long long*)((char*)Ah + boff) = *(unsigned long long*)h4;
  }
  __syncthreads();

  const int wid = tid >> 6, lane = tid & 63;
  const int kg8 = (lane >> 4) * 8;
  f32x4 acc[2][2];
  #pragma unroll
  for (int mi = 0; mi < 2; ++mi)
    #pragma unroll
    for (int nf = 0; nf < 2; ++nf) acc[mi][nf] = (f32x4){0.f,0.f,0.f,0.f};

  #pragma unroll
  for (int s = 0; s < 6; ++s){
    const int kk = s*32 + kg8;
    const int t = kk / 48, c0 = kk - t*48;
    const int ra = t >> 1, ca = t & 1;
    f16x8 ah[2];
    #pragma unroll
    for (int mi = 0; mi < 2; ++mi){
      const int m = 2*wid + mi;
      const int rowsel = m >> 2;
      const int ow = (m & 3)*16 + (lane & 15);
      const int owc = ow > 55 ? 55 : ow;
      const int col = owc + ca;
      const int bidx = ((((rowsel + ra)*58 + col) << 7) + c0*2) ^ ((col & 7) << 4);
      ah[mi] = *(const f16x8*)((const char*)Ah + bidx);
    }
    #pragma unroll
    for (int nf = 0; nf < 2; ++nf){
      const f16x8 bw = *(const f16x8*)(W + (s*2 + nf)*512 + lane*8);
      #pragma unroll
      for (int mi = 0; mi < 2; ++mi)
        acc[mi][nf] = __builtin_amdgcn_mfma_f32_16x16x32_f16(ah[mi], bw, acc[mi][nf], 0,0,0);
    }
  }

  const int oc = lane & 15;
  const float sbv = sb[oc];
  const float scv = g[oc] * __frsqrt_rn(vr[oc] + 1e-5f);
  const float mnv = mn[oc], btv = bt[oc], cbv = cb_[oc];
  #pragma unroll
  for (int mi = 0; mi < 2; ++mi){
    const int m = 2*wid + mi;
    const int row = oh0 + (m >> 2);
    const int owb = (m & 3)*16 + (lane >> 4)*4;
    #pragma unroll
    for (int r = 0; r < 4; ++r){
      const int ow = owb + r;
      if (ow >= 56) continue;
      float vs = acc[mi][0][r] + sbv;
      vs = fmaxf((vs - mnv)*scv + btv, 0.f);
      const size_t o = (((size_t)n*56 + row)*56 + ow)*16 + oc;
      s1out[o] = (_Float16)vs;
      c1out[o] = (_Float16)leakyf(acc[mi][1][r] + cbv);
    }
  }
}

// ---------------- strided (S=2) MFMA conv, fp16 NHWC input [B,IH,IW,16] -----
// GATE: fuse BN+relu then spatial-sum -> atomicAdd gsum[n*32+oc] (no tensor out)
// else OUT16: fp16 NHWC out ; else fp32 NHWC out
template<int OC,int K,int P,int IH,int IW,int ACT,bool OUT16,bool GATE>
__global__ __launch_bounds__(256) void convS_k(
    const _Float16* __restrict__ in,
    const _Float16* __restrict__ W,
    const float* __restrict__ bias,
    const float* __restrict__ bng, const float* __restrict__ bnb,
    const float* __restrict__ bnm, const float* __restrict__ bnv,
    float* __restrict__ outF, _Float16* __restrict__ outH,
    float* __restrict__ gsum){
  constexpr int F = OC/16, KWP = (K+1)/2;
  __shared__ __align__(16) _Float16 A[K*60*16];
  __shared__ float gred[32];

  const int tid = threadIdx.x;
  const int n = blockIdx.x / 28, oh = blockIdx.x % 28;

  if (GATE && tid < 32) gred[tid] = 0.f;

  for (int i = tid; i < K*60*2; i += 256){
    int half = i & 1; int p = i >> 1;
    int c = p % 60; int r = p / 60;
    int ih = 2*oh - P + r, iw = c - P;
    int4 v = {0,0,0,0};
    if (ih >= 0 && ih < IH && iw >= 0 && iw < IW)
      v = *(const int4*)(in + (((size_t)n*IH + ih)*IW + iw)*16 + half*8);
    int byte = ((r*60 + c)*32 + half*16) ^ (((c>>1)&7) << 4);
    *(int4*)((char*)A + byte) = v;
  }
  __syncthreads();

  const int wid = tid >> 6, lane = tid & 63;
  const int fsel = wid & 1, mb = wid >> 1;
  const int ow_l = min(mb*16 + (lane & 15), 27);
  const int ic0b = ((lane >> 4) & 1) * 16;
  const int kwo  = (lane >> 4) >> 1;

  f32x4 acc = {0.f,0.f,0.f,0.f};
  #pragma unroll
  for (int kh = 0; kh < K; ++kh){
    #pragma unroll
    for (int kwp = 0; kwp < KWP; ++kwp){
      const int kw = 2*kwp + kwo;
      const int c = 2*ow_l + kw;
      int byte = ((kh*60 + c)*32 + ic0b) ^ (((c>>1)&7) << 4);
      f16x8 a = *(const f16x8*)((const char*)A + byte);
      const int s = kh*KWP + kwp;
      const f16x8 b = *(const f16x8*)(W + (s*F + fsel)*512 + lane*8);
      acc = __builtin_amdgcn_mfma_f32_16x16x32_f16(a, b, acc, 0,0,0);
    }
  }

  const int oc = fsel*16 + (lane & 15);
  float bv = bias[oc], sc = 1.f, mm = 0.f, bb = 0.f;
  if (ACT == 1){
    sc = bng[oc] * __frsqrt_rn(bnv[oc] + 1e-5f);
    mm = bnm[oc]; bb = bnb[oc];
  }
  float lsum = 0.f;
  #pragma unroll
  for (int r = 0; r < 4; ++r){
    const int ow = mb*16 + (lane >> 4)*4 + r;
    if (ow >= 28) continue;
    float v = acc[r] + bv;
    if (ACT == 1) v = fmaxf((v - mm)*sc + bb, 0.f);
    else          v = leakyf(v);
    if (GATE){
      lsum += v;
    } else {
      const size_t o = (((size_t)n*28 + oh)*28 + ow)*OC + oc;
      if (OUT16) outH[o] = (_Float16)v;
      else       outF[o] = v;
    }
  }
  if (GATE){
    atomicAdd(&gred[oc], lsum);
    __syncthreads();
    if (tid < 32) atomicAdd(&gsum[n*32 + tid], gred[tid]);
  }
}

// ---------------- MFMA single-fp16 3x3 s1 p1 conv on 27x27, padded NHWC -----
template<int IC,int OC,int OUTM>
__global__ __launch_bounds__(256) void convM_k(
    const _Float16* __restrict__ Ag,
    const _Float16* __restrict__ W,
    const float* __restrict__ bias,
    _Float16* __restrict__ OutPad, _Float16* __restrict__ OutNP)
{
  constexpr int S = IC/32, FTOT = OC/16, FW = FTOT/2;
  constexpr int ICB = IC*2, ICG = ICB/16;
  __shared__ __align__(16) char A[4*34*ICB];

  const int tid = threadIdx.x;
  const int bx = blockIdx.x;
  const int n = bx / 14, pr = bx % 14;
  const int oh0 = pr * 2;

  const size_t gbase = ((size_t)n*29) * 29 * IC;
  for (int g = tid; g < 4*34*ICG; g += 256){
    int r = g / (34*ICG);
    int rem = g - r*(34*ICG);
    int c = rem / ICG, q = rem - c*ICG;
    int rp = oh0 + r;
    int4 v = {0,0,0,0};
    if (rp <= 28 && c < 29){
      size_t e = gbase + ((size_t)rp*29 + c)*IC + q*8;
      v = *(const int4*)(Ag + e);
    }
    int off = (r*34 + c)*ICB + q*16;
    int swz = off ^ ((c & 7) << 4);
    *(int4*)(A + swz) = v;
  }
  __syncthreads();

  const int wid = tid >> 6, lane = tid & 63;
  const int rsel = wid & 1, ocq = wid >> 1;
  const int c0 = lane & 15, kg = (lane >> 4) * 16;
  const int colb0 = c0*ICB + kg, colb1 = (16 + c0)*ICB + kg;
  int msk[3];
  #pragma unroll
  for (int kw = 0; kw < 3; ++kw) msk[kw] = ((c0 + kw) & 7) << 4;

  f32x4 acc[2][FW];
  #pragma unroll
  for (int m = 0; m < 2; ++m)
    #pragma unroll
    for (int f = 0; f < FW; ++f) acc[m][f] = (f32x4){0.f,0.f,0.f,0.f};

  #pragma unroll
  for (int kh = 0; kh < 3; ++kh){
    #pragma unroll
    for (int kw = 0; kw < 3; ++kw){
      #pragma unroll
      for (int s = 0; s < S; ++s){
        const int fr0 = (((kh*3 + kw)*S + s)*FTOT + ocq*FW) * 512 + lane*8;
        f16x8 b[FW];
        #pragma unroll
        for (int f = 0; f < FW; ++f)
          b[f] = *(const f16x8*)(W + fr0 + f*512);
        const int base = ((rsel + kh)*34 + kw)*ICB + s*64;
        const int o0 = (base + colb0) ^ msk[kw];
        const int o1 = (base + colb1) ^ msk[kw];
        f16x8 a0 = *(const f16x8*)(A + o0);
        f16x8 a1 = *(const f16x8*)(A + o1);
        #pragma unroll
        for (int f = 0; f < FW; ++f){
          acc[0][f] = __builtin_amdgcn_mfma_f32_16x16x32_f16(a0, b[f], acc[0][f], 0,0,0);
          acc[1][f] = __builtin_amdgcn_mfma_f32_16x16x32_f16(a1, b[f], acc[1][f], 0,0,0);
        }
      }
    }
  }

  const int orow = oh0 + rsel;
  if (orow >= 27) return;
  #pragma unroll
  for (int f = 0; f < FW; ++f){
    const int oc = (ocq*FW + f)*16 + c0;
    const float bv = bias[oc];
    #pragma unroll
    for (int m = 0; m < 2; ++m){
      #pragma unroll
      for (int r = 0; r < 4; ++r){
        const int ow = m*16 + (lane >> 4)*4 + r;
        if (ow >= 27) continue;
        float v = leakyf(acc[m][f][r] + bv);
        if (OUTM == 0){
          OutPad[(((size_t)n*29 + orow+1)*29 + ow+1)*OC + oc] = (_Float16)v;
        } else {
          OutNP[(((size_t)n*27 + orow)*27 + ow)*OC + oc] = (_Float16)v;
        }
      }
    }
  }
}

// ---------------- single-fp16 MFMA GEMM for MoE head ------------------------
template<int KTOT,int ACT,int OUTM>
__global__ __launch_bounds__(256) void gemmH_k(
    const _Float16* __restrict__ A, long strideA,
    const _Float16* __restrict__ W,
    const float* __restrict__ bias, int N,
    _Float16* __restrict__ OutH, float* __restrict__ OutF){
  const int e = blockIdx.z;
  A += (size_t)e * strideA;
  const int NF = N >> 4, KT = KTOT >> 5;
  W += (size_t)e * NF * KT * 512;
  const float* bs = bias + (size_t)e * N;
  const size_t ob = (size_t)e * 256 * N;

  const int tid = threadIdx.x, wid = tid >> 6, lane = tid & 63;
  const int mblk = blockIdx.x * 32;
  const int nf = blockIdx.y * 4 + wid;
  const int r0 = mblk + (lane & 15);
  const int kof = (lane >> 4) * 8;

  f32x4 acc0 = {0,0,0,0}, acc1 = {0,0,0,0};
  for (int t = 0; t < KT; ++t){
    const int k = t*32 + kof;
    f16x8 a0 = *(const f16x8*)(A + (size_t)r0*KTOT + k);
    f16x8 a1 = *(const f16x8*)(A + (size_t)(r0+16)*KTOT + k);
    const f16x8 b = *(const f16x8*)(W + ((size_t)t*NF + nf)*512 + lane*8);
    acc0 = __builtin_amdgcn_mfma_f32_16x16x32_f16(a0, b, acc0, 0,0,0);
    acc1 = __builtin_amdgcn_mfma_f32_16x16x32_f16(a1, b, acc1, 0,0,0);
  }
  const int n = nf*16 + (lane & 15);
  const float bv = bs[n];
  #pragma unroll
  for (int mi = 0; mi < 2; ++mi){
    f32x4 a = mi ? acc1 : acc0;
    #pragma unroll
    for (int r = 0; r < 4; ++r){
      const int m = mblk + mi*16 + (lane >> 4)*4 + r;
      float v = a[r] + bv;
      if (ACT == 1) v = leakyf(v);
      const size_t o = ob + (size_t)m*N + n;
      if (OUTM == 0) OutH[o] = (_Float16)v;
      else           OutF[o] = v;
    }
  }
}

// ------ fp16 NHWC 2x2 s1 maxpool: [B,56,56,16] -> [B,55,55,16] --------------
__global__ __launch_bounds__(256) void poolh_k(const _Float16* __restrict__ in,
                                               _Float16* __restrict__ out){
  int idx = blockIdx.x * 256 + threadIdx.x;
  if (idx >= BATCH * 55 * 55 * 2) return;
  int half = idx & 1; int p = idx >> 1;
  int ow = p % 55; int t = p / 55; int oh = t % 55; int n = t / 55;
  const _Float16* q = in + (((size_t)n*56 + oh)*56 + ow)*16 + half*8;
  f16x8 a = *(const f16x8*)q;
  f16x8 b = *(const f16x8*)(q + 16);
  f16x8 c = *(const f16x8*)(q + 56*16);
  f16x8 d = *(const f16x8*)(q + 57*16);
  f16x8 r;
  #pragma unroll
  for (int j = 0; j < 8; ++j){
    float m = fmaxf(fmaxf((float)a[j], (float)b[j]), fmaxf((float)c[j], (float)d[j]));
    r[j] = (_Float16)m;
  }
  *(f16x8*)(out + (size_t)p*16 + half*8) = r;
}

// ------- pool2: fp16 NHWC [B,28,28,32] -> padded NHWC fp16 [B,29,29,32] -----
__global__ __launch_bounds__(256) void pool2n_k(const _Float16* __restrict__ in,
    _Float16* __restrict__ o16){
  int idx = blockIdx.x*256 + threadIdx.x;
  if (idx >= BATCH*27*27*32) return;
  int ic = idx & 31; int p = idx >> 5;
  int ow = p % 27; int t = p / 27; int oh = t % 27; int n = t / 27;
  const _Float16* b = in + (((size_t)n*28 + oh)*28 + ow)*32 + ic;
  float v = fmaxf(fmaxf((float)b[0], (float)b[32]),
                  fmaxf((float)b[28*32], (float)b[29*32]));
  o16[(((size_t)n*29 + oh+1)*29 + ow+1)*32 + ic] = (_Float16)v;
}

// ---------------- gate from fused sums: [B,32] -> comb[B,3] -----------------
__global__ __launch_bounds__(256) void gate2_k(const float* __restrict__ gsum,
                                               const float* __restrict__ cw,
                                               const float* __restrict__ cb,
                                               float* __restrict__ comb){
  int n = blockIdx.x * 256 + threadIdx.x;
  if (n >= BATCH) return;
  float mch[32];
  #pragma unroll
  for (int c = 0; c < 32; ++c) mch[c] = gsum[n*32 + c] / 784.f;
  float lg[3];
  #pragma unroll
  for (int e = 0; e < 3; ++e){
    float a = cb[e];
    #pragma unroll
    for (int c = 0; c < 32; ++c) a += mch[c] * cw[e*32 + c];
    lg[e] = a;
  }
  float m = fmaxf(lg[0], fmaxf(lg[1], lg[2]));
  float ex[3], sum = 0.f;
  #pragma unroll
  for (int e = 0; e < 3; ++e){ ex[e] = expf(lg[e] - m); sum += ex[e]; }
  float pr[3];
  #pragma unroll
  for (int e = 0; e < 3; ++e) pr[e] = ex[e] / sum;
  int i1 = 0;
  if (pr[1] > pr[0]) i1 = 1;
  if (pr[2] > pr[i1]) i1 = 2;
  int i2 = -1;
  for (int e = 0; e < 3; ++e){
    if (e == i1) continue;
    if (i2 < 0 || pr[e] > pr[i2]) i2 = e;
  }
  float s12 = pr[i1] + pr[i2] + 1e-6f;
  float cmb[3] = {0.f, 0.f, 0.f};
  cmb[i1] = pr[i1] / s12;
  cmb[i2] = pr[i2] / s12;
  comb[n*3 + 0] = cmb[0];
  comb[n*3 + 1] = cmb[1];
  comb[n*3 + 2] = cmb[2];
}

// ------ channel-parallel fused maxpool2s1(27->26) + adaptive avg(26->3) -----
__global__ __launch_bounds__(256) void papool2_k(const _Float16* __restrict__ in,
                                                 float* __restrict__ flat){
  __shared__ float red[2][128][9];
  const int n = blockIdx.x;
  const int tid = threadIdx.x;
  const int h = tid >> 7, c = tid & 127;
  const _Float16* p = in + (size_t)n * 729 * 128 + c;

  float sum[9];
  #pragma unroll
  for (int j = 0; j < 9; ++j) sum[j] = 0.f;

  float prev[27], cur[27];
  const int r0 = h * 13;
  #pragma unroll
  for (int rr = 0; rr < 14; ++rr){
    const int r = r0 + rr;
    #pragma unroll
    for (int cc = 0; cc < 27; ++cc)
      cur[cc] = (float)p[(size_t)(r*27 + cc) * 128];
    if (rr > 0){
      const int pr = r - 1;
      const bool b0 = (pr < 9), b1 = (pr >= 8) && (pr < 18), b2 = (pr >= 17);
      #pragma unroll
      for (int cc = 0; cc < 26; ++cc){
        float v = fmaxf(fmaxf(prev[cc], prev[cc+1]), fmaxf(cur[cc], cur[cc+1]));
        if (b0){
          if (cc < 9)             sum[0] += v;
          if (cc >= 8 && cc < 18) sum[1] += v;
          if (cc >= 17)           sum[2] += v;
        }
        if (b1){
          if (cc < 9)             sum[3] += v;
          if (cc >= 8 && cc < 18) sum[4] += v;
          if (cc >= 17)           sum[5] += v;
        }
        if (b2){
          if (cc < 9)             sum[6] += v;
          if (cc >= 8 && cc < 18) sum[7] += v;
          if (cc >= 17)           sum[8] += v;
        }
      }
    }
    #pragma unroll
    for (int cc = 0; cc < 27; ++cc) prev[cc] = cur[cc];
  }

  #pragma unroll
  for (int j = 0; j < 9; ++j) red[h][c][j] = sum[j];
  __syncthreads();

  if (tid < 128){
    const float rcp[9] = {1.f/81, 1.f/90, 1.f/81, 1.f/90, 1.f/100, 1.f/90,
                          1.f/81, 1.f/90, 1.f/81};
    float* o = flat + (size_t)n * 1152 + tid * 9;
    #pragma unroll
    for (int j = 0; j < 9; ++j)
      o[j] = (red[0][tid][j] + red[1][tid][j]) * rcp[j];
  }
}

// ---------------- final gated combine ----------------
__global__ __launch_bounds__(256) void comb_k(const float* __restrict__ h3,
                                              const float* __restrict__ comb,
                                              float* __restrict__ out){
  int idx = blockIdx.x * 256 + threadIdx.x;
  if (idx >= BATCH * 512) return;
  int o = idx % 512, b = idx / 512;
  float s = 0.f;
  #pragma unroll
  for (int e = 0; e < 3; ++e)
    s += comb[b * 3 + e] * h3[((size_t)e * BATCH + b) * 512 + o];
  out[idx] = s;
}

// ============================================================================
extern "C" void kernel_launch(void* const* d_in, const int* in_sizes, int n_in,
                              void* d_out, int out_size, void* d_ws, size_t ws_size,
                              hipStream_t stream){
  const float* x    = (const float*)d_in[0];
  const float* tw1  = (const float*)d_in[1];  const float* tb1 = (const float*)d_in[2];
  const float* tw2  = (const float*)d_in[3];  const float* tb2 = (const float*)d_in[4];
  const float* tw3  = (const float*)d_in[5];  const float* tb3 = (const float*)d_in[6];
  const float* tw4  = (const float*)d_in[7];  const float* tb4 = (const float*)d_in[8];
  const float* sw1  = (const float*)d_in[9];  const float* sb1 = (const float*)d_in[10];
  const float* bn1g = (const float*)d_in[11]; const float* bn1b = (const float*)d_in[12];
  const float* bn1m = (const float*)d_in[13]; const float* bn1v = (const float*)d_in[14];
  const float* sw2  = (const float*)d_in[15]; const float* sb2 = (const float*)d_in[16];
  const float* bn2g = (const float*)d_in[17]; const float* bn2b = (const float*)d_in[18];
  const float* bn2m = (const float*)d_in[19]; const float* bn2v = (const float*)d_in[20];
  const float* cw   = (const float*)d_in[21]; const float* cb  = (const float*)d_in[22];
  const float* ew1  = (const float*)d_in[23]; const float* eb1 = (const float*)d_in[24];
  const float* ew2  = (const float*)d_in[25]; const float* eb2 = (const float*)d_in[26];
  const float* ew3  = (const float*)d_in[27]; const float* eb3 = (const float*)d_in[28];
  float* out = (float*)d_out;

  // ---- workspace layout (floats), ~157 MB ----
  float* ws = (float*)d_ws;
  size_t off = 0;
  float* comb   = ws + off; off += 768;
  float* flat   = ws + off; off += (size_t)BATCH * 1152;
  float* h3     = ws + off; off += (size_t)BATCH * 3 * 512;
  float* gsum   = ws + off; off += BATCH * 32;            // scout gate sums
  _Float16* wpk3 = (_Float16*)(ws + off); off += 9216;
  _Float16* wpk4 = (_Float16*)(ws + off); off += 36864;
  _Float16* wp2  = (_Float16*)(ws + off); off += 7680;
  _Float16* wps2 = (_Float16*)(ws + off); off += 3072;
  _Float16* wpf  = (_Float16*)(ws + off); off += 3072;
  off += 16;                                                      // guard pad
  float* bufA   = ws + off; off += 13778944;
  off += 16;                                                      // guard pad
  float* bufB   = ws + off; off += 23887872;
  off += 16;
  (void)ws_size; (void)in_sizes; (void)n_in; (void)out_size;

  // phase aliases (lifetimes disjoint, single-stream ordered)
  _Float16* s1h = (_Float16*)bufA;           // [B,56,56,16] fp16 NHWC
  _Float16* c1h = (_Float16*)bufB;           // [B,56,56,16] fp16 NHWC
  _Float16* p1h = (_Float16*)bufA;           // [B,55,55,16] fp16 NHWC
  _Float16* c2h = (_Float16*)bufB;           // [B,28,28,32] fp16 NHWC
  _Float16* P2 = (_Float16*)(bufB + 8000000);
  _Float16* C3 = (_Float16*)bufA;
  _Float16* c4h = (_Float16*)bufB;           // [B,27,27,128] fp16 NHWC

  // head-phase aliases in bufB (valid after papool2_k) — all fp16
  _Float16* hb = (_Float16*)bufB;
  size_t uo = 0;
  _Float16* ewp1 = hb + uo; uo += 3538944;
  _Float16* ewp2 = hb + uo; uo += 1572864;
  _Float16* ewp3 = hb + uo; uo += 786432;
  _Float16* f16a = hb + uo; uo += 294912;
  _Float16* h1   = hb + uo; uo += 786432;
  _Float16* h2   = hb + uo; uo += 393216;

  dim3 blk(256);

  // ---- weight prep + gate accumulator zero ----
  hipMemsetAsync(gsum, 0, BATCH * 32 * sizeof(float), stream);
  wpackM_k<32,64>  <<<dim3(72),  blk, 0, stream>>>(tw3, wpk3);
  wpackM_k<64,128> <<<dim3(288), blk, 0, stream>>>(tw4, wpk4);
  wpackS_k<32,5><<<dim3(60), blk, 0, stream>>>(tw2, wp2);
  wpackS_k<32,3><<<dim3(24), blk, 0, stream>>>(sw2, wps2);
  wpackF_k<<<dim3(24), blk, 0, stream>>>(sw1, tw1, wpf);

  // ---- fused scout1 + conv1 -> fp16 NHWC (2 rows/block, proven) ----
  fusedM_k<<<dim3(BATCH*28), blk, 0, stream>>>(
      x, wpf, sb1, tb1, bn1g, bn1b, bn1m, bn1v, s1h, c1h);

  // ---- scout2 fused with gate spatial-sum (no tensor output) ----
  convS_k<32,3,1,56,56,1,false,true><<<dim3(BATCH*28), blk, 0, stream>>>(
      s1h, wps2, sb2, bn2g, bn2b, bn2m, bn2v, nullptr, nullptr, gsum);
  gate2_k<<<dim3(1), blk, 0, stream>>>(gsum, cw, cb, comb);

  // ---- pool1 (fp16 NHWC) -> conv2 (fp16 out) ----
  poolh_k<<<dim3((BATCH*55*55*2 + 255)/256), blk, 0, stream>>>(c1h, p1h);
  convS_k<32,5,2,55,55,0,true,false><<<dim3(BATCH*28), blk, 0, stream>>>(
      p1h, wp2, tb2, nullptr, nullptr, nullptr, nullptr, nullptr, c2h, nullptr);

  // ---- pool2 (fp16 in) -> padded NHWC fp16 ----
  hipMemsetAsync(P2, 0, (size_t)6889472 * 2, stream);
  pool2n_k<<<dim3((BATCH*27*27*32 + 255)/256), blk, 0, stream>>>(c2h, P2);

  // ---- conv3 (MFMA fp16) -> padded NHWC fp16 ----
  hipMemsetAsync(C3, 0, (size_t)13778944 * 2, stream);
  convM_k<32,64,0><<<dim3(BATCH*14), blk, 0, stream>>>(
      P2, wpk3, tb3, C3, nullptr);

  // ---- conv4 (MFMA fp16) -> fp16 NHWC [B,27,27,128] ----
  convM_k<64,128,1><<<dim3(BATCH*14), blk, 0, stream>>>(
      C3, wpk4, tb4, nullptr, c4h);

  papool2_k<<<dim3(BATCH), blk, 0, stream>>>(c4h, flat);

  // ---- MoE head: pack weights fp16 + convert A, then 3 fp16 MFMA GEMMs ----
  wpackGh_k<1152><<<dim3(4608,3), blk, 0, stream>>>(ew1, 1024, ewp1);
  wpackGh_k<1024><<<dim3(2048,3), blk, 0, stream>>>(ew2,  512, ewp2);
  wpackGh_k< 512><<<dim3(1024,3), blk, 0, stream>>>(ew3,  512, ewp3);
  acvt_k<<<dim3(1152), blk, 0, stream>>>(flat, f16a, BATCH*1152);

  gemmH_k<1152,1,0><<<dim3(8,16,3), blk, 0, stream>>>(
      f16a, 0L, ewp1, eb1, 1024, h1, nullptr);
  gemmH_k<1024,1,0><<<dim3(8,8,3), blk, 0, stream>>>(
      h1, 256L*1024, ewp2, eb2, 512, h2, nullptr);
  gemmH_k< 512,0,1><<<dim3(8,8,3), blk, 0, stream>>>(
      h2, 256L*512, ewp3, eb3, 512, nullptr, h3);

  comb_k<<<dim3(512), blk, 0, stream>>>(h3, comb, out);
}

// Round 18
// 301.713 us; speedup vs baseline: 1.0496x; 1.0177x over previous
//
#include <hip/hip_runtime.h>

#define DEV static __device__ __forceinline__

constexpr int BATCH = 256;

DEV float leakyf(float x){ return x > 0.f ? x : 0.2f * x; }

typedef _Float16 f16x8 __attribute__((ext_vector_type(8)));
typedef float f32x4 __attribute__((ext_vector_type(4)));

// ------- pack OIHW conv weights into MFMA B-fragment order, single fp16 -----
template<int IC,int OC>
__global__ __launch_bounds__(256) void wpackM_k(const float* __restrict__ w,
    _Float16* __restrict__ wp){
  constexpr int S = IC/32, F = OC/16;
  int i = blockIdx.x*256 + threadIdx.x;
  if (i >= 9*S*F*512) return;
  int j = i & 7, L = (i >> 3) & 63, rest = i >> 9;
  int f = rest % F; int q2 = rest / F; int s = q2 % S; int t = q2 / S;
  int oc = f*16 + (L & 15), ic = s*32 + (L >> 4)*8 + j;
  wp[i] = (_Float16)w[((size_t)oc*IC + ic)*9 + t];
}

// ------- pack strided-conv weights (IC=16), single fp16 ---------------------
template<int OC,int K>
__global__ __launch_bounds__(256) void wpackS_k(const float* __restrict__ w,
    _Float16* __restrict__ wp){
  constexpr int F = OC/16, KWP = (K+1)/2;
  int i = blockIdx.x*256 + threadIdx.x;
  if (i >= K*KWP*F*512) return;
  int j = i & 7, L = (i >> 3) & 63, rest = i >> 9;
  int f = rest % F, s = rest / F;
  int kh = s / KWP, kwp = s % KWP;
  int k = (L >> 4)*8 + j;
  int kw = 2*kwp + (k >> 4), ic = k & 15;
  int oc = f*16 + (L & 15);
  float v = (kw < K) ? w[((size_t)(oc*16 + ic)*K + kh)*K + kw] : 0.f;
  wp[i] = (_Float16)v;
}

// ------- pack scout1(k7) + conv1(k3) weights, space-to-depth, single fp16 ---
__global__ __launch_bounds__(256) void wpackF_k(const float* __restrict__ sw1,
    const float* __restrict__ tw1, _Float16* __restrict__ wp){
  int i = blockIdx.x*256 + threadIdx.x;
  if (i >= 6*2*512) return;
  int j = i & 7, L = (i >> 3) & 63, rest = i >> 9;
  int nf = rest & 1, s = rest >> 1;
  int k = s*32 + (L >> 4)*8 + j;
  int oc = L & 15;
  int t = k / 48, c = k % 48;
  int dr = (t >> 1) - 1, dc = (t & 1) - 1;
  int ic = c >> 4, pr = (c >> 2) & 3, pc = c & 3;
  float v = 0.f;
  if (nf == 0){
    int kh = 4*dr + pr + 3, kw = 4*dc + pc + 3;
    if (kh >= 0 && kh < 7 && kw >= 0 && kw < 7) v = sw1[((oc*3 + ic)*7 + kh)*7 + kw];
  } else {
    int kh = 4*dr + pr + 1, kw = 4*dc + pc + 1;
    if (kh >= 0 && kh < 3 && kw >= 0 && kw < 3) v = tw1[((oc*3 + ic)*3 + kh)*3 + kw];
  }
  wp[i] = (_Float16)v;
}

// ------- pack expert GEMM weights W[e][N][K] into frag order, single fp16 ---
template<int KTOT>
__global__ __launch_bounds__(256) void wpackGh_k(const float* __restrict__ w, int N,
    _Float16* __restrict__ wp){
  const int NF = N >> 4, KT = KTOT >> 5;
  const int total = NF * KT * 512;
  const int e = blockIdx.y;
  w  += (size_t)e * N * KTOT;
  wp += (size_t)e * total;
  int i = blockIdx.x*256 + threadIdx.x;
  if (i >= total) return;
  int j = i & 7, L = (i >> 3) & 63, rest = i >> 9;
  int nf = rest % NF, t = rest / NF;
  int n = nf*16 + (L & 15), k = t*32 + (L >> 4)*8 + j;
  wp[i] = (_Float16)w[(size_t)n*KTOT + k];
}

// ------- convert fp32 array to fp16 ----------------------------------------
__global__ __launch_bounds__(256) void acvt_k(const float* __restrict__ in,
    _Float16* __restrict__ o16, int nelem){
  int i = blockIdx.x*256 + threadIdx.x;
  if (i >= nelem) return;
  o16[i] = (_Float16)in[i];
}

// ---------- fused scout1+conv1, space-to-depth MFMA fp16, SINGLE barrier ----
// Zero only col0/col57 slots (disjoint from staging); staging writes zeros
// for ih<0 rows (ih>=224 provably unreachable). One __syncthreads().
__global__ __launch_bounds__(256) void fusedM_k(
    const float* __restrict__ x,
    const _Float16* __restrict__ W,
    const float* __restrict__ sb, const float* __restrict__ cb_,
    const float* __restrict__ g, const float* __restrict__ bt,
    const float* __restrict__ mn, const float* __restrict__ vr,
    _Float16* __restrict__ s1out, _Float16* __restrict__ c1out){
  __shared__ __align__(16) _Float16 Ah[3*58*64];
  const int tid = threadIdx.x;
  const int n = blockIdx.x / 28, oh0 = (blockIdx.x % 28) * 2;

  // zero border cols 0 and 57 (full 128B slots; swizzle is a permutation
  // within the slot, so covering all 8 int4 chunks suffices)
  if (tid < 48){
    int rr = tid >> 4, side = (tid >> 3) & 1, q = tid & 7;
    int col = side ? 57 : 0;
    *(int4*)((char*)Ah + (((rr*58 + col) << 7) + q*16)) = (int4){0,0,0,0};
  }

  // stage 12 x-rows x 3 ic x 224 cols; zeros for ih<0 (only at oh0==0)
  for (int i = tid; i < 2016; i += 256){
    int m = i % 56; int rc = i / 56;
    int ic = rc % 3, ridx = rc / 3;
    int ih = 4*oh0 - 4 + ridx;
    float4 v = {0.f,0.f,0.f,0.f};
    if (ih >= 0)
      v = *(const float4*)(x + ((size_t)(n*3 + ic)*224 + ih)*224 + 4*m);
    int rr = ridx >> 2, pr = ridx & 3, cc = m + 1;
    int boff = (((rr*58 + cc) << 7) + ic*32 + pr*8) ^ ((cc & 7) << 4);
    _Float16 h4[4] = {(_Float16)v.x, (_Float16)v.y, (_Float16)v.z, (_Float16)v.w};
    *(unsigned long long*)((char*)Ah + boff) = *(unsigned long long*)h4;
  }
  __syncthreads();

  const int wid = tid >> 6, lane = tid & 63;
  const int kg8 = (lane >> 4) * 8;
  f32x4 acc[2][2];
  #pragma unroll
  for (int mi = 0; mi < 2; ++mi)
    #pragma unroll
    for (int nf = 0; nf < 2; ++nf) acc[mi][nf] = (f32x4){0.f,0.f,0.f,0.f};

  #pragma unroll
  for (int s = 0; s < 6; ++s){
    const int kk = s*32 + kg8;
    const int t = kk / 48, c0 = kk - t*48;
    const int ra = t >> 1, ca = t & 1;
    f16x8 ah[2];
    #pragma unroll
    for (int mi = 0; mi < 2; ++mi){
      const int m = 2*wid + mi;
      const int rowsel = m >> 2;
      const int ow = (m & 3)*16 + (lane & 15);
      const int owc = ow > 55 ? 55 : ow;
      const int col = owc + ca;
      const int bidx = ((((rowsel + ra)*58 + col) << 7) + c0*2) ^ ((col & 7) << 4);
      ah[mi] = *(const f16x8*)((const char*)Ah + bidx);
    }
    #pragma unroll
    for (int nf = 0; nf < 2; ++nf){
      const f16x8 bw = *(const f16x8*)(W + (s*2 + nf)*512 + lane*8);
      #pragma unroll
      for (int mi = 0; mi < 2; ++mi)
        acc[mi][nf] = __builtin_amdgcn_mfma_f32_16x16x32_f16(ah[mi], bw, acc[mi][nf], 0,0,0);
    }
  }

  const int oc = lane & 15;
  const float sbv = sb[oc];
  const float scv = g[oc] * __frsqrt_rn(vr[oc] + 1e-5f);
  const float mnv = mn[oc], btv = bt[oc], cbv = cb_[oc];
  #pragma unroll
  for (int mi = 0; mi < 2; ++mi){
    const int m = 2*wid + mi;
    const int row = oh0 + (m >> 2);
    const int owb = (m & 3)*16 + (lane >> 4)*4;
    #pragma unroll
    for (int r = 0; r < 4; ++r){
      const int ow = owb + r;
      if (ow >= 56) continue;
      float vs = acc[mi][0][r] + sbv;
      vs = fmaxf((vs - mnv)*scv + btv, 0.f);
      const size_t o = (((size_t)n*56 + row)*56 + ow)*16 + oc;
      s1out[o] = (_Float16)vs;
      c1out[o] = (_Float16)leakyf(acc[mi][1][r] + cbv);
    }
  }
}

// ---------------- strided (S=2) MFMA conv, fp16 NHWC input [B,IH,IW,16] -----
// GATE: fuse BN+relu then spatial-sum -> atomicAdd gsum[n*32+oc] (no tensor out)
template<int OC,int K,int P,int IH,int IW,int ACT,bool OUT16,bool GATE>
__global__ __launch_bounds__(256) void convS_k(
    const _Float16* __restrict__ in,
    const _Float16* __restrict__ W,
    const float* __restrict__ bias,
    const float* __restrict__ bng, const float* __restrict__ bnb,
    const float* __restrict__ bnm, const float* __restrict__ bnv,
    float* __restrict__ outF, _Float16* __restrict__ outH,
    float* __restrict__ gsum){
  constexpr int F = OC/16, KWP = (K+1)/2;
  __shared__ __align__(16) _Float16 A[K*60*16];
  __shared__ float gred[32];

  const int tid = threadIdx.x;
  const int n = blockIdx.x / 28, oh = blockIdx.x % 28;

  if (GATE && tid < 32) gred[tid] = 0.f;

  for (int i = tid; i < K*60*2; i += 256){
    int half = i & 1; int p = i >> 1;
    int c = p % 60; int r = p / 60;
    int ih = 2*oh - P + r, iw = c - P;
    int4 v = {0,0,0,0};
    if (ih >= 0 && ih < IH && iw >= 0 && iw < IW)
      v = *(const int4*)(in + (((size_t)n*IH + ih)*IW + iw)*16 + half*8);
    int byte = ((r*60 + c)*32 + half*16) ^ (((c>>1)&7) << 4);
    *(int4*)((char*)A + byte) = v;
  }
  __syncthreads();

  const int wid = tid >> 6, lane = tid & 63;
  const int fsel = wid & 1, mb = wid >> 1;
  const int ow_l = min(mb*16 + (lane & 15), 27);
  const int ic0b = ((lane >> 4) & 1) * 16;
  const int kwo  = (lane >> 4) >> 1;

  f32x4 acc = {0.f,0.f,0.f,0.f};
  #pragma unroll
  for (int kh = 0; kh < K; ++kh){
    #pragma unroll
    for (int kwp = 0; kwp < KWP; ++kwp){
      const int kw = 2*kwp + kwo;
      const int c = 2*ow_l + kw;
      int byte = ((kh*60 + c)*32 + ic0b) ^ (((c>>1)&7) << 4);
      f16x8 a = *(const f16x8*)((const char*)A + byte);
      const int s = kh*KWP + kwp;
      const f16x8 b = *(const f16x8*)(W + (s*F + fsel)*512 + lane*8);
      acc = __builtin_amdgcn_mfma_f32_16x16x32_f16(a, b, acc, 0,0,0);
    }
  }

  const int oc = fsel*16 + (lane & 15);
  float bv = bias[oc], sc = 1.f, mm = 0.f, bb = 0.f;
  if (ACT == 1){
    sc = bng[oc] * __frsqrt_rn(bnv[oc] + 1e-5f);
    mm = bnm[oc]; bb = bnb[oc];
  }
  float lsum = 0.f;
  #pragma unroll
  for (int r = 0; r < 4; ++r){
    const int ow = mb*16 + (lane >> 4)*4 + r;
    if (ow >= 28) continue;
    float v = acc[r] + bv;
    if (ACT == 1) v = fmaxf((v - mm)*sc + bb, 0.f);
    else          v = leakyf(v);
    if (GATE){
      lsum += v;
    } else {
      const size_t o = (((size_t)n*28 + oh)*28 + ow)*OC + oc;
      if (OUT16) outH[o] = (_Float16)v;
      else       outF[o] = v;
    }
  }
  if (GATE){
    atomicAdd(&gred[oc], lsum);
    __syncthreads();
    if (tid < 32) atomicAdd(&gsum[n*32 + tid], gred[tid]);
  }
}

// ---------------- MFMA single-fp16 3x3 s1 p1 conv on 27x27, padded NHWC -----
template<int IC,int OC,int OUTM>
__global__ __launch_bounds__(256) void convM_k(
    const _Float16* __restrict__ Ag,
    const _Float16* __restrict__ W,
    const float* __restrict__ bias,
    _Float16* __restrict__ OutPad, _Float16* __restrict__ OutNP)
{
  constexpr int S = IC/32, FTOT = OC/16, FW = FTOT/2;
  constexpr int ICB = IC*2, ICG = ICB/16;
  __shared__ __align__(16) char A[4*34*ICB];

  const int tid = threadIdx.x;
  const int bx = blockIdx.x;
  const int n = bx / 14, pr = bx % 14;
  const int oh0 = pr * 2;

  const size_t gbase = ((size_t)n*29) * 29 * IC;
  for (int g = tid; g < 4*34*ICG; g += 256){
    int r = g / (34*ICG);
    int rem = g - r*(34*ICG);
    int c = rem / ICG, q = rem - c*ICG;
    int rp = oh0 + r;
    int4 v = {0,0,0,0};
    if (rp <= 28 && c < 29){
      size_t e = gbase + ((size_t)rp*29 + c)*IC + q*8;
      v = *(const int4*)(Ag + e);
    }
    int off = (r*34 + c)*ICB + q*16;
    int swz = off ^ ((c & 7) << 4);
    *(int4*)(A + swz) = v;
  }
  __syncthreads();

  const int wid = tid >> 6, lane = tid & 63;
  const int rsel = wid & 1, ocq = wid >> 1;
  const int c0 = lane & 15, kg = (lane >> 4) * 16;
  const int colb0 = c0*ICB + kg, colb1 = (16 + c0)*ICB + kg;
  int msk[3];
  #pragma unroll
  for (int kw = 0; kw < 3; ++kw) msk[kw] = ((c0 + kw) & 7) << 4;

  f32x4 acc[2][FW];
  #pragma unroll
  for (int m = 0; m < 2; ++m)
    #pragma unroll
    for (int f = 0; f < FW; ++f) acc[m][f] = (f32x4){0.f,0.f,0.f,0.f};

  #pragma unroll
  for (int kh = 0; kh < 3; ++kh){
    #pragma unroll
    for (int kw = 0; kw < 3; ++kw){
      #pragma unroll
      for (int s = 0; s < S; ++s){
        const int fr0 = (((kh*3 + kw)*S + s)*FTOT + ocq*FW) * 512 + lane*8;
        f16x8 b[FW];
        #pragma unroll
        for (int f = 0; f < FW; ++f)
          b[f] = *(const f16x8*)(W + fr0 + f*512);
        const int base = ((rsel + kh)*34 + kw)*ICB + s*64;
        const int o0 = (base + colb0) ^ msk[kw];
        const int o1 = (base + colb1) ^ msk[kw];
        f16x8 a0 = *(const f16x8*)(A + o0);
        f16x8 a1 = *(const f16x8*)(A + o1);
        #pragma unroll
        for (int f = 0; f < FW; ++f){
          acc[0][f] = __builtin_amdgcn_mfma_f32_16x16x32_f16(a0, b[f], acc[0][f], 0,0,0);
          acc[1][f] = __builtin_amdgcn_mfma_f32_16x16x32_f16(a1, b[f], acc[1][f], 0,0,0);
        }
      }
    }
  }

  const int orow = oh0 + rsel;
  if (orow >= 27) return;
  #pragma unroll
  for (int f = 0; f < FW; ++f){
    const int oc = (ocq*FW + f)*16 + c0;
    const float bv = bias[oc];
    #pragma unroll
    for (int m = 0; m < 2; ++m){
      #pragma unroll
      for (int r = 0; r < 4; ++r){
        const int ow = m*16 + (lane >> 4)*4 + r;
        if (ow >= 27) continue;
        float v = leakyf(acc[m][f][r] + bv);
        if (OUTM == 0){
          OutPad[(((size_t)n*29 + orow+1)*29 + ow+1)*OC + oc] = (_Float16)v;
        } else {
          OutNP[(((size_t)n*27 + orow)*27 + ow)*OC + oc] = (_Float16)v;
        }
      }
    }
  }
}

// ---------------- single-fp16 MFMA GEMM for MoE head ------------------------
template<int KTOT,int ACT,int OUTM>
__global__ __launch_bounds__(256) void gemmH_k(
    const _Float16* __restrict__ A, long strideA,
    const _Float16* __restrict__ W,
    const float* __restrict__ bias, int N,
    _Float16* __restrict__ OutH, float* __restrict__ OutF){
  const int e = blockIdx.z;
  A += (size_t)e * strideA;
  const int NF = N >> 4, KT = KTOT >> 5;
  W += (size_t)e * NF * KT * 512;
  const float* bs = bias + (size_t)e * N;
  const size_t ob = (size_t)e * 256 * N;

  const int tid = threadIdx.x, wid = tid >> 6, lane = tid & 63;
  const int mblk = blockIdx.x * 32;
  const int nf = blockIdx.y * 4 + wid;
  const int r0 = mblk + (lane & 15);
  const int kof = (lane >> 4) * 8;

  f32x4 acc0 = {0,0,0,0}, acc1 = {0,0,0,0};
  for (int t = 0; t < KT; ++t){
    const int k = t*32 + kof;
    f16x8 a0 = *(const f16x8*)(A + (size_t)r0*KTOT + k);
    f16x8 a1 = *(const f16x8*)(A + (size_t)(r0+16)*KTOT + k);
    const f16x8 b = *(const f16x8*)(W + ((size_t)t*NF + nf)*512 + lane*8);
    acc0 = __builtin_amdgcn_mfma_f32_16x16x32_f16(a0, b, acc0, 0,0,0);
    acc1 = __builtin_amdgcn_mfma_f32_16x16x32_f16(a1, b, acc1, 0,0,0);
  }
  const int n = nf*16 + (lane & 15);
  const float bv = bs[n];
  #pragma unroll
  for (int mi = 0; mi < 2; ++mi){
    f32x4 a = mi ? acc1 : acc0;
    #pragma unroll
    for (int r = 0; r < 4; ++r){
      const int m = mblk + mi*16 + (lane >> 4)*4 + r;
      float v = a[r] + bv;
      if (ACT == 1) v = leakyf(v);
      const size_t o = ob + (size_t)m*N + n;
      if (OUTM == 0) OutH[o] = (_Float16)v;
      else           OutF[o] = v;
    }
  }
}

// ------ fp16 NHWC 2x2 s1 maxpool: [B,56,56,16] -> [B,55,55,16] --------------
__global__ __launch_bounds__(256) void poolh_k(const _Float16* __restrict__ in,
                                               _Float16* __restrict__ out){
  int idx = blockIdx.x * 256 + threadIdx.x;
  if (idx >= BATCH * 55 * 55 * 2) return;
  int half = idx & 1; int p = idx >> 1;
  int ow = p % 55; int t = p / 55; int oh = t % 55; int n = t / 55;
  const _Float16* q = in + (((size_t)n*56 + oh)*56 + ow)*16 + half*8;
  f16x8 a = *(const f16x8*)q;
  f16x8 b = *(const f16x8*)(q + 16);
  f16x8 c = *(const f16x8*)(q + 56*16);
  f16x8 d = *(const f16x8*)(q + 57*16);
  f16x8 r;
  #pragma unroll
  for (int j = 0; j < 8; ++j){
    float m = fmaxf(fmaxf((float)a[j], (float)b[j]), fmaxf((float)c[j], (float)d[j]));
    r[j] = (_Float16)m;
  }
  *(f16x8*)(out + (size_t)p*16 + half*8) = r;
}

// ------- pool2: fp16 NHWC [B,28,28,32] -> padded NHWC fp16 [B,29,29,32] -----
__global__ __launch_bounds__(256) void pool2n_k(const _Float16* __restrict__ in,
    _Float16* __restrict__ o16){
  int idx = blockIdx.x*256 + threadIdx.x;
  if (idx >= BATCH*27*27*32) return;
  int ic = idx & 31; int p = idx >> 5;
  int ow = p % 27; int t = p / 27; int oh = t % 27; int n = t / 27;
  const _Float16* b = in + (((size_t)n*28 + oh)*28 + ow)*32 + ic;
  float v = fmaxf(fmaxf((float)b[0], (float)b[32]),
                  fmaxf((float)b[28*32], (float)b[29*32]));
  o16[(((size_t)n*29 + oh+1)*29 + ow+1)*32 + ic] = (_Float16)v;
}

// ---------------- gate from fused sums: [B,32] -> comb[B,3] -----------------
__global__ __launch_bounds__(256) void gate2_k(const float* __restrict__ gsum,
                                               const float* __restrict__ cw,
                                               const float* __restrict__ cb,
                                               float* __restrict__ comb){
  int n = blockIdx.x * 256 + threadIdx.x;
  if (n >= BATCH) return;
  float mch[32];
  #pragma unroll
  for (int c = 0; c < 32; ++c) mch[c] = gsum[n*32 + c] / 784.f;
  float lg[3];
  #pragma unroll
  for (int e = 0; e < 3; ++e){
    float a = cb[e];
    #pragma unroll
    for (int c = 0; c < 32; ++c) a += mch[c] * cw[e*32 + c];
    lg[e] = a;
  }
  float m = fmaxf(lg[0], fmaxf(lg[1], lg[2]));
  float ex[3], sum = 0.f;
  #pragma unroll
  for (int e = 0; e < 3; ++e){ ex[e] = expf(lg[e] - m); sum += ex[e]; }
  float pr[3];
  #pragma unroll
  for (int e = 0; e < 3; ++e) pr[e] = ex[e] / sum;
  int i1 = 0;
  if (pr[1] > pr[0]) i1 = 1;
  if (pr[2] > pr[i1]) i1 = 2;
  int i2 = -1;
  for (int e = 0; e < 3; ++e){
    if (e == i1) continue;
    if (i2 < 0 || pr[e] > pr[i2]) i2 = e;
  }
  float s12 = pr[i1] + pr[i2] + 1e-6f;
  float cmb[3] = {0.f, 0.f, 0.f};
  cmb[i1] = pr[i1] / s12;
  cmb[i2] = pr[i2] / s12;
  comb[n*3 + 0] = cmb[0];
  comb[n*3 + 1] = cmb[1];
  comb[n*3 + 2] = cmb[2];
}

// ------ channel-parallel fused maxpool2s1(27->26) + adaptive avg(26->3) -----
__global__ __launch_bounds__(256) void papool2_k(const _Float16* __restrict__ in,
                                                 float* __restrict__ flat){
  __shared__ float red[2][128][9];
  const int n = blockIdx.x;
  const int tid = threadIdx.x;
  const int h = tid >> 7, c = tid & 127;
  const _Float16* p = in + (size_t)n * 729 * 128 + c;

  float sum[9];
  #pragma unroll
  for (int j = 0; j < 9; ++j) sum[j] = 0.f;

  float prev[27], cur[27];
  const int r0 = h * 13;
  #pragma unroll
  for (int rr = 0; rr < 14; ++rr){
    const int r = r0 + rr;
    #pragma unroll
    for (int cc = 0; cc < 27; ++cc)
      cur[cc] = (float)p[(size_t)(r*27 + cc) * 128];
    if (rr > 0){
      const int pr = r - 1;
      const bool b0 = (pr < 9), b1 = (pr >= 8) && (pr < 18), b2 = (pr >= 17);
      #pragma unroll
      for (int cc = 0; cc < 26; ++cc){
        float v = fmaxf(fmaxf(prev[cc], prev[cc+1]), fmaxf(cur[cc], cur[cc+1]));
        if (b0){
          if (cc < 9)             sum[0] += v;
          if (cc >= 8 && cc < 18) sum[1] += v;
          if (cc >= 17)           sum[2] += v;
        }
        if (b1){
          if (cc < 9)             sum[3] += v;
          if (cc >= 8 && cc < 18) sum[4] += v;
          if (cc >= 17)           sum[5] += v;
        }
        if (b2){
          if (cc < 9)             sum[6] += v;
          if (cc >= 8 && cc < 18) sum[7] += v;
          if (cc >= 17)           sum[8] += v;
        }
      }
    }
    #pragma unroll
    for (int cc = 0; cc < 27; ++cc) prev[cc] = cur[cc];
  }

  #pragma unroll
  for (int j = 0; j < 9; ++j) red[h][c][j] = sum[j];
  __syncthreads();

  if (tid < 128){
    const float rcp[9] = {1.f/81, 1.f/90, 1.f/81, 1.f/90, 1.f/100, 1.f/90,
                          1.f/81, 1.f/90, 1.f/81};
    float* o = flat + (size_t)n * 1152 + tid * 9;
    #pragma unroll
    for (int j = 0; j < 9; ++j)
      o[j] = (red[0][tid][j] + red[1][tid][j]) * rcp[j];
  }
}

// ---------------- final gated combine ----------------
__global__ __launch_bounds__(256) void comb_k(const float* __restrict__ h3,
                                              const float* __restrict__ comb,
                                              float* __restrict__ out){
  int idx = blockIdx.x * 256 + threadIdx.x;
  if (idx >= BATCH * 512) return;
  int o = idx % 512, b = idx / 512;
  float s = 0.f;
  #pragma unroll
  for (int e = 0; e < 3; ++e)
    s += comb[b * 3 + e] * h3[((size_t)e * BATCH + b) * 512 + o];
  out[idx] = s;
}

// ============================================================================
extern "C" void kernel_launch(void* const* d_in, const int* in_sizes, int n_in,
                              void* d_out, int out_size, void* d_ws, size_t ws_size,
                              hipStream_t stream){
  const float* x    = (const float*)d_in[0];
  const float* tw1  = (const float*)d_in[1];  const float* tb1 = (const float*)d_in[2];
  const float* tw2  = (const float*)d_in[3];  const float* tb2 = (const float*)d_in[4];
  const float* tw3  = (const float*)d_in[5];  const float* tb3 = (const float*)d_in[6];
  const float* tw4  = (const float*)d_in[7];  const float* tb4 = (const float*)d_in[8];
  const float* sw1  = (const float*)d_in[9];  const float* sb1 = (const float*)d_in[10];
  const float* bn1g = (const float*)d_in[11]; const float* bn1b = (const float*)d_in[12];
  const float* bn1m = (const float*)d_in[13]; const float* bn1v = (const float*)d_in[14];
  const float* sw2  = (const float*)d_in[15]; const float* sb2 = (const float*)d_in[16];
  const float* bn2g = (const float*)d_in[17]; const float* bn2b = (const float*)d_in[18];
  const float* bn2m = (const float*)d_in[19]; const float* bn2v = (const float*)d_in[20];
  const float* cw   = (const float*)d_in[21]; const float* cb  = (const float*)d_in[22];
  const float* ew1  = (const float*)d_in[23]; const float* eb1 = (const float*)d_in[24];
  const float* ew2  = (const float*)d_in[25]; const float* eb2 = (const float*)d_in[26];
  const float* ew3  = (const float*)d_in[27]; const float* eb3 = (const float*)d_in[28];
  float* out = (float*)d_out;

  // ---- workspace layout (floats), ~157 MB ----
  float* ws = (float*)d_ws;
  size_t off = 0;
  float* comb   = ws + off; off += 768;
  float* flat   = ws + off; off += (size_t)BATCH * 1152;
  float* h3     = ws + off; off += (size_t)BATCH * 3 * 512;
  float* gsum   = ws + off; off += BATCH * 32;            // scout gate sums
  _Float16* wpk3 = (_Float16*)(ws + off); off += 9216;
  _Float16* wpk4 = (_Float16*)(ws + off); off += 36864;
  _Float16* wp2  = (_Float16*)(ws + off); off += 7680;
  _Float16* wps2 = (_Float16*)(ws + off); off += 3072;
  _Float16* wpf  = (_Float16*)(ws + off); off += 3072;
  off += 16;                                                      // guard pad
  float* bufA   = ws + off; off += 13778944;
  off += 16;                                                      // guard pad
  float* bufB   = ws + off; off += 23887872;
  off += 16;
  (void)ws_size; (void)in_sizes; (void)n_in; (void)out_size;

  // phase aliases (lifetimes disjoint, single-stream ordered)
  _Float16* s1h = (_Float16*)bufA;           // [B,56,56,16] fp16 NHWC
  _Float16* c1h = (_Float16*)bufB;           // [B,56,56,16] fp16 NHWC
  _Float16* p1h = (_Float16*)bufA;           // [B,55,55,16] fp16 NHWC
  _Float16* c2h = (_Float16*)bufB;           // [B,28,28,32] fp16 NHWC
  _Float16* P2 = (_Float16*)(bufB + 8000000);
  _Float16* C3 = (_Float16*)bufA;
  _Float16* c4h = (_Float16*)bufB;           // [B,27,27,128] fp16 NHWC

  // head-phase aliases in bufB (valid after papool2_k) — all fp16
  _Float16* hb = (_Float16*)bufB;
  size_t uo = 0;
  _Float16* ewp1 = hb + uo; uo += 3538944;
  _Float16* ewp2 = hb + uo; uo += 1572864;
  _Float16* ewp3 = hb + uo; uo += 786432;
  _Float16* f16a = hb + uo; uo += 294912;
  _Float16* h1   = hb + uo; uo += 786432;
  _Float16* h2   = hb + uo; uo += 393216;

  dim3 blk(256);

  // ---- weight prep + gate accumulator zero ----
  hipMemsetAsync(gsum, 0, BATCH * 32 * sizeof(float), stream);
  wpackM_k<32,64>  <<<dim3(72),  blk, 0, stream>>>(tw3, wpk3);
  wpackM_k<64,128> <<<dim3(288), blk, 0, stream>>>(tw4, wpk4);
  wpackS_k<32,5><<<dim3(60), blk, 0, stream>>>(tw2, wp2);
  wpackS_k<32,3><<<dim3(24), blk, 0, stream>>>(sw2, wps2);
  wpackF_k<<<dim3(24), blk, 0, stream>>>(sw1, tw1, wpf);

  // ---- fused scout1 + conv1 -> fp16 NHWC (single-barrier) ----
  fusedM_k<<<dim3(BATCH*28), blk, 0, stream>>>(
      x, wpf, sb1, tb1, bn1g, bn1b, bn1m, bn1v, s1h, c1h);

  // ---- scout2 fused with gate spatial-sum (no tensor output) ----
  convS_k<32,3,1,56,56,1,false,true><<<dim3(BATCH*28), blk, 0, stream>>>(
      s1h, wps2, sb2, bn2g, bn2b, bn2m, bn2v, nullptr, nullptr, gsum);
  gate2_k<<<dim3(1), blk, 0, stream>>>(gsum, cw, cb, comb);

  // ---- pool1 (fp16 NHWC) -> conv2 (fp16 out) ----
  poolh_k<<<dim3((BATCH*55*55*2 + 255)/256), blk, 0, stream>>>(c1h, p1h);
  convS_k<32,5,2,55,55,0,true,false><<<dim3(BATCH*28), blk, 0, stream>>>(
      p1h, wp2, tb2, nullptr, nullptr, nullptr, nullptr, nullptr, c2h, nullptr);

  // ---- pool2 (fp16 in) -> padded NHWC fp16 ----
  hipMemsetAsync(P2, 0, (size_t)6889472 * 2, stream);
  pool2n_k<<<dim3((BATCH*27*27*32 + 255)/256), blk, 0, stream>>>(c2h, P2);

  // ---- conv3 (MFMA fp16) -> padded NHWC fp16 ----
  hipMemsetAsync(C3, 0, (size_t)13778944 * 2, stream);
  convM_k<32,64,0><<<dim3(BATCH*14), blk, 0, stream>>>(
      P2, wpk3, tb3, C3, nullptr);

  // ---- conv4 (MFMA fp16) -> fp16 NHWC [B,27,27,128] ----
  convM_k<64,128,1><<<dim3(BATCH*14), blk, 0, stream>>>(
      C3, wpk4, tb4, nullptr, c4h);

  papool2_k<<<dim3(BATCH), blk, 0, stream>>>(c4h, flat);

  // ---- MoE head: pack weights fp16 + convert A, then 3 fp16 MFMA GEMMs ----
  wpackGh_k<1152><<<dim3(4608,3), blk, 0, stream>>>(ew1, 1024, ewp1);
  wpackGh_k<1024><<<dim3(2048,3), blk, 0, stream>>>(ew2,  512, ewp2);
  wpackGh_k< 512><<<dim3(1024,3), blk, 0, stream>>>(ew3,  512, ewp3);
  acvt_k<<<dim3(1152), blk, 0, stream>>>(flat, f16a, BATCH*1152);

  gemmH_k<1152,1,0><<<dim3(8,16,3), blk, 0, stream>>>(
      f16a, 0L, ewp1, eb1, 1024, h1, nullptr);
  gemmH_k<1024,1,0><<<dim3(8,8,3), blk, 0, stream>>>(
      h1, 256L*1024, ewp2, eb2, 512, h2, nullptr);
  gemmH_k< 512,0,1><<<dim3(8,8,3), blk, 0, stream>>>(
      h2, 256L*512, ewp3, eb3, 512, nullptr, h3);

  comb_k<<<dim3(512), blk, 0, stream>>>(h3, comb, out);
}